// Round 20
// baseline (317.889 us; speedup 1.0000x reference)
//
#include <hip/hip_runtime.h>

using f32x4  = __attribute__((ext_vector_type(4))) float;
using bf16x8 = __attribute__((ext_vector_type(8))) __bf16;

#define AS1(p) ((__attribute__((address_space(1))) void*)(p))
#define AS3(p) ((__attribute__((address_space(3))) void*)(p))

__device__ __forceinline__ unsigned short f2bf(float f) {
    unsigned u = __float_as_uint(f);
    unsigned r = u + 0x7FFFu + ((u >> 16) & 1u);
    return (unsigned short)(r >> 16);
}

__device__ __forceinline__ unsigned cvtpk(float lo, float hi) {
    unsigned r;
    asm("v_cvt_pk_bf16_f32 %0, %1, %2" : "=v"(r) : "v"(lo), "v"(hi));
    return r;
}

__device__ __forceinline__ f32x4 mfma16(bf16x8 a, bf16x8 b, f32x4 c) {
    return __builtin_amdgcn_mfma_f32_16x16x32_bf16(a, b, c, 0, 0, 0);
}

// ---------------- streaming prep: hidden cvt + enc pad/cvt + KV-buffer zero-fill ----------------
__global__ void k_stream(const float* __restrict__ hidden, unsigned short* __restrict__ hid_bf,
                         const float* __restrict__ enc, const float* __restrict__ qual,
                         unsigned short* __restrict__ encp, uint4* __restrict__ kvzero) {
    const long N_HID = 5242880;               // 41,943,040 / 8
    const long N_ENC = 819200;                // x4 elems
    const long N_Z   = 409600;                // 6,553,600 B / 16
    const long total = N_HID + N_ENC + N_Z;
    long i0 = (long)blockIdx.x * 256 + threadIdx.x;
    long stride = (long)gridDim.x * 256;
    for (long i = i0; i < total; i += stride) {
        if (i < N_HID) {
            long e = i * 8;
            float4 a = *(const float4*)&hidden[e];
            float4 b = *(const float4*)&hidden[e + 4];
            uint4 v;
            v.x = cvtpk(a.x, a.y);
            v.y = cvtpk(a.z, a.w);
            v.z = cvtpk(b.x, b.y);
            v.w = cvtpk(b.z, b.w);
            *(uint4*)&hid_bf[e] = v;
        } else if (i < N_HID + N_ENC) {
            long e = (i - N_HID) * 4;
            int g = (int)(e / (1280L * 1280));
            long rem = e - (long)g * 1280 * 1280;
            int m = (int)(rem / 1280);
            uint2 v = {0u, 0u};
            if (m < 1232) {
                const float* src = (g ? qual : enc) + rem;
                float4 a = *(const float4*)src;
                v.x = f2bf(a.x) | ((unsigned)f2bf(a.y) << 16);
                v.y = f2bf(a.z) | ((unsigned)f2bf(a.w) << 16);
            }
            *(uint2*)&encp[e] = v;
        } else {
            kvzero[i - N_HID - N_ENC] = uint4{0u, 0u, 0u, 0u};
        }
    }
}

// ---------------- LDS-tile weight transpose: coalesced reads AND writes ----------------
__global__ __launch_bounds__(256) void k_transpose_w(
    const float* __restrict__ Wq, const float* __restrict__ Wout,
    const float* __restrict__ Wks, const float* __restrict__ Wvs,
    const float* __restrict__ Wkq, const float* __restrict__ Wvq,
    unsigned short* __restrict__ wq_bt, unsigned short* __restrict__ wout_bt,
    unsigned short* __restrict__ wkv_bt) {
    const int z = blockIdx.z;
    const float* src; unsigned short* dst; int K; int nbase; float scale = 1.0f;
    switch (z) {
        case 0:  src = Wq;  dst = wq_bt;             K = 640;  nbase = 0;
                 scale = 0.11180339887498949f; break;
        case 1:  src = Wout; dst = wout_bt;          K = 640;  nbase = 0;   break;
        case 2:  src = Wks; dst = wkv_bt;            K = 1280; nbase = 0;   break;
        case 3:  src = Wvs; dst = wkv_bt;            K = 1280; nbase = 640; break;
        case 4:  src = Wkq; dst = wkv_bt + 1638400;  K = 1280; nbase = 0;   break;
        default: src = Wvq; dst = wkv_bt + 1638400;  K = 1280; nbase = 640; break;
    }
    const int k0 = blockIdx.x * 64;
    if (k0 >= K) return;
    const int n0 = blockIdx.y * 64;
    __shared__ float t[64][65];
    const int r4 = threadIdx.x >> 6, c = threadIdx.x & 63;
#pragma unroll
    for (int it = 0; it < 16; ++it) {
        int r = r4 + 4 * it;
        t[r][c] = src[(size_t)(k0 + r) * 640 + n0 + c];   // coalesced 256B rows
    }
    __syncthreads();
#pragma unroll
    for (int it = 0; it < 16; ++it) {
        int n = r4 + 4 * it;
        dst[(size_t)(nbase + n0 + n) * K + k0 + c] = f2bf(t[c][n] * scale);  // coalesced 128B rows
    }
}

// ---------------- GEMM: BK=32, 2-phase counted double-buffer (32 KB LDS), XOR-swizzle ----------------
// Same LDS footprint as the measured-best single-buffer BK=64 (5 blocks/CU), but stage(t+1)
// is in flight across a full compute phase -> vmcnt(0) at iter t+1 finds it landed.

template <int OUT_F32, int SWZ>
__global__ __launch_bounds__(256) void gemm_bt(
    const unsigned short* __restrict__ A, const unsigned short* __restrict__ Bt,
    void* __restrict__ Cv, int K, int N, long zA, long zB, long zC)
{
    size_t m0; int n0;
    if (SWZ) {
        int i = blockIdx.x;
        int L = (i & 7) * 320 + (i >> 3);   // 2560 blocks, 8 XCDs, 320 per XCD
        n0 = (L % 5) * 128;
        m0 = (size_t)(L / 5) * 128;
    } else {
        m0 = (size_t)blockIdx.x * 128;
        n0 = blockIdx.y * 128;
    }
    const unsigned short* Ab = A + (size_t)blockIdx.z * zA;
    const unsigned short* Bb = Bt + (size_t)blockIdx.z * zB;
    __shared__ __attribute__((aligned(16))) unsigned short As[2][128 * 32];
    __shared__ __attribute__((aligned(16))) unsigned short Bs[2][128 * 32];
    const int tid = threadIdx.x, lane = tid & 63, wv = tid >> 6;
    const int wm = wv >> 1, wn = wv & 1;
    const int srow = lane >> 2;                          // row within 16-row chunk
    const int scol = ((lane & 3) ^ (srow & 3)) * 8;      // swizzled source col (shorts)
    f32x4 acc[4][4] = {};
    const int nt = K >> 5;

#define GBT_STAGE(T, BUF)                                                                     \
    {                                                                                         \
        int kk0 = (T) << 5;                                                                   \
        for (int c = wv; c < 8; c += 4) {                                                     \
            __builtin_amdgcn_global_load_lds(AS1(Ab + (m0 + c * 16 + srow) * K + kk0 + scol), \
                                             AS3(&As[BUF][c * 512]), 16, 0, 0);               \
            __builtin_amdgcn_global_load_lds(                                                 \
                AS1(Bb + ((size_t)(n0 + c * 16 + srow)) * K + kk0 + scol),                    \
                AS3(&Bs[BUF][c * 512]), 16, 0, 0);                                            \
        }                                                                                     \
    }

    GBT_STAGE(0, 0);
    int cb = 0;
    for (int t = 0; t < nt; ++t) {
        asm volatile("s_waitcnt vmcnt(0)" ::: "memory");  // stage(t) landed (issued last iter)
        __syncthreads();
        if (t + 1 < nt) GBT_STAGE(t + 1, cb ^ 1);         // in flight across this compute
        const int q = lane >> 4, l15 = lane & 15;
        bf16x8 a[4], b[4];
#pragma unroll
        for (int i = 0; i < 4; ++i) {
            int ra = wm * 64 + i * 16 + l15;
            int rb = wn * 64 + i * 16 + l15;
            a[i] = *(const bf16x8*)&As[cb][ra * 32 + ((q ^ (ra & 3)) * 8)];
            b[i] = *(const bf16x8*)&Bs[cb][rb * 32 + ((q ^ (rb & 3)) * 8)];
        }
#pragma unroll
        for (int mi = 0; mi < 4; ++mi)
#pragma unroll
            for (int ni = 0; ni < 4; ++ni)
                acc[mi][ni] = mfma16(a[mi], b[ni], acc[mi][ni]);
        cb ^= 1;
    }
#undef GBT_STAGE

#pragma unroll
    for (int mi = 0; mi < 4; ++mi) {
#pragma unroll
        for (int ni = 0; ni < 4; ++ni) {
            size_t row = m0 + wm * 64 + mi * 16 + ((lane >> 4) * 4);
            int col = n0 + wn * 64 + ni * 16 + (lane & 15);
#pragma unroll
            for (int i = 0; i < 4; ++i) {
                float v = acc[mi][ni][i];
                if (OUT_F32)
                    ((float*)Cv + (size_t)blockIdx.z * zC)[(row + i) * N + col] = v;
                else
                    ((unsigned short*)Cv + (size_t)blockIdx.z * zC)[(row + i) * N + col] = f2bf(v);
            }
        }
    }
}

// ---------------- KV GEMM 64x128 with fused scatter epilogue ----------------
__global__ __launch_bounds__(256) void gemm_kv(
    const unsigned short* __restrict__ A, const unsigned short* __restrict__ Bt,
    unsigned short* __restrict__ Kg2, unsigned short* __restrict__ Vt2)
{
    const size_t m0 = (size_t)blockIdx.x * 64;
    const int n0 = blockIdx.y * 128;
    const int g = blockIdx.z;
    const unsigned short* Ab = A + (size_t)g * 1638400;
    const unsigned short* Bb = Bt + (size_t)g * 1638400;
    __shared__ __attribute__((aligned(16))) unsigned short As[64 * 32];
    __shared__ __attribute__((aligned(16))) unsigned short Bs[128 * 32];
    const int tid = threadIdx.x, lane = tid & 63, wv = tid >> 6;
    const int srow = lane >> 2;
    const int scol = ((lane & 3) ^ (srow & 3)) * 8;
    f32x4 acc[4][2] = {};
    for (int k0 = 0; k0 < 1280; k0 += 32) {
        {
            int c = wv;
            __builtin_amdgcn_global_load_lds(AS1(Ab + (m0 + c * 16 + srow) * 1280 + k0 + scol),
                                             AS3(&As[c * 512]), 16, 0, 0);
        }
        for (int c = wv; c < 8; c += 4)
            __builtin_amdgcn_global_load_lds(AS1(Bb + ((size_t)(n0 + c * 16 + srow)) * 1280 + k0 + scol),
                                             AS3(&Bs[c * 512]), 16, 0, 0);
        asm volatile("s_waitcnt vmcnt(0)" ::: "memory");
        __syncthreads();
        const int q = lane >> 4, l15 = lane & 15;
        bf16x8 a[4], b[2];
#pragma unroll
        for (int i = 0; i < 4; ++i) {
            int ra = i * 16 + l15;
            a[i] = *(const bf16x8*)&As[ra * 32 + ((q ^ (ra & 3)) * 8)];
        }
#pragma unroll
        for (int j = 0; j < 2; ++j) {
            int rb = wv * 32 + j * 16 + l15;
            b[j] = *(const bf16x8*)&Bs[rb * 32 + ((q ^ (rb & 3)) * 8)];
        }
#pragma unroll
        for (int mi = 0; mi < 4; ++mi)
#pragma unroll
            for (int ni = 0; ni < 2; ++ni)
                acc[mi][ni] = mfma16(a[mi], b[ni], acc[mi][ni]);
        __syncthreads();
    }
#pragma unroll
    for (int mi = 0; mi < 4; ++mi) {
#pragma unroll
        for (int ni = 0; ni < 2; ++ni) {
            int col = n0 + wv * 32 + ni * 16 + (lane & 15);
#pragma unroll
            for (int i = 0; i < 4; ++i) {
                int row = (int)m0 + mi * 16 + ((lane >> 4) * 4) + i;
                if (row < 1232) {
                    int b = row / 77, l = row - b * 77;
                    unsigned short val = f2bf(acc[mi][ni][i]);
                    if (col < 640) {
                        int h = col / 80, d = col - h * 80;
                        Kg2[(((size_t)g * 16 + b) * 8 + h) * 6400 + l * 80 + d] = val;
                    } else {
                        int c2 = col - 640;
                        int h = c2 / 80, d = c2 - h * 80;
                        Vt2[(((size_t)g * 16 + b) * 8 + h) * 6400 + d * 80 + l] = val;
                    }
                }
            }
        }
    }
}

// ---------------- fused dual attention: software-pipelined S-cluster lookahead ----------------
__global__ __launch_bounds__(512, 4) void attn_kernel(
    const unsigned short* __restrict__ Q,    // [16][4096][640] bf16 (pre-scaled via Wq)
    const unsigned short* __restrict__ Kg2,  // [2][16][8][80][80]
    const unsigned short* __restrict__ Vt2,  // [2][16][8][80][80]
    const float* __restrict__ fw,            // [2]
    unsigned short* __restrict__ fused)      // [16][4096][640] bf16
{
    const int b = blockIdx.z, h = blockIdx.y;
    const int s0 = blockIdx.x * 512;
    __shared__ __attribute__((aligned(16))) unsigned short lds[25600 + 8 * 1408];
    const int tid = threadIdx.x, lane = tid & 63, wv = tid >> 6;
    const int l15 = lane & 15, q = lane >> 4;

    // ---- stage K/V (4 slabs x 800 chunks of 16B), LDS linear
    {
        const unsigned short* sK0 = Kg2 + (size_t)(b * 8 + h) * 6400;
        const unsigned short* sK1 = Kg2 + (size_t)((16 + b) * 8 + h) * 6400;
        const unsigned short* sV0 = Vt2 + (size_t)(b * 8 + h) * 6400;
        const unsigned short* sV1 = Vt2 + (size_t)((16 + b) * 8 + h) * 6400;
#pragma unroll
        for (int it = 0; it < 7; ++it) {
            int chunk = it * 512 + tid;
            if (chunk < 3200) {
                const unsigned short* src = sK0 + (size_t)chunk * 8;
                if (chunk >= 800)  src = sK1 + (size_t)(chunk - 800) * 8;
                if (chunk >= 1600) src = sV0 + (size_t)(chunk - 1600) * 8;
                if (chunk >= 2400) src = sV1 + (size_t)(chunk - 2400) * 8;
                __builtin_amdgcn_global_load_lds(AS1(src), AS3(&lds[(it * 512 + wv * 64) * 8]),
                                                 16, 0, 0);
            }
        }
    }
    asm volatile("s_waitcnt vmcnt(0)" ::: "memory");
    __syncthreads();

    float f0 = fw[0], f1 = fw[1];
    float fm = fmaxf(f0, f1);
    float e0 = __expf(f0 - fm), e1 = __expf(f1 - fm);
    float w0 = e0 / (e0 + e1), w1 = e1 / (e0 + e1);

    unsigned short* obuf = &lds[25600 + wv * 1408];   // per-wave [16][88]

    bf16x8 aq[3];
    f32x4 sA[5], sB[5], o[5];
#pragma unroll
    for (int t = 0; t < 5; ++t) o[t] = f32x4{};

#define AQ_LOAD(RG)                                                                          \
    {                                                                                        \
        const unsigned short* qrow =                                                         \
            Q + ((size_t)b * 4096 + s0 + wv * 64 + (RG) * 16 + l15) * 640 + h * 80;          \
        aq[0] = *(const bf16x8*)(qrow + q * 8);                                              \
        aq[1] = *(const bf16x8*)(qrow + 32 + q * 8);                                         \
        if (q < 2) aq[2] = *(const bf16x8*)(qrow + 64 + q * 8);                              \
        else       aq[2] = bf16x8{};                                                         \
    }

#define SC(G, S)                                                                             \
    {                                                                                        \
        const unsigned short* Ks = &lds[(G) * 6400];                                         \
        _Pragma("unroll") for (int t = 0; t < 5; ++t) S[t] = f32x4{};                        \
        __builtin_amdgcn_s_setprio(1);                                                       \
        _Pragma("unroll") for (int t = 0; t < 5; ++t)                                        \
            _Pragma("unroll") for (int kk = 0; kk < 3; ++kk) {                               \
                bf16x8 ak;                                                                   \
                if (kk < 2 || q < 2)                                                         \
                    ak = *(const bf16x8*)&Ks[(t * 16 + l15) * 80 + kk * 32 + q * 8];         \
                else ak = bf16x8{};                                                          \
                S[t] = mfma16(ak, aq[kk], S[t]);                                             \
            }                                                                                \
        __builtin_amdgcn_s_setprio(0);                                                       \
    }

#define PROC(G, S)                                                                           \
    {                                                                                        \
        float sum = 0.f;                                                                     \
        _Pragma("unroll") for (int t = 0; t < 4; ++t)                                        \
            _Pragma("unroll") for (int i = 0; i < 4; ++i) {                                  \
                S[t][i] = __expf(S[t][i]); sum += S[t][i];                                   \
            }                                                                                \
        _Pragma("unroll") for (int i = 0; i < 4; ++i) {                                      \
            S[4][i] = (q * 4 + i < 13) ? __expf(S[4][i]) : 0.f;                              \
            sum += S[4][i];                                                                  \
        }                                                                                    \
        sum += __shfl_xor(sum, 16);                                                          \
        sum += __shfl_xor(sum, 32);                                                          \
        float rw = ((G) ? w1 : w0) / sum;                                                    \
        uint2 myq[5];                                                                        \
        _Pragma("unroll") for (int t = 0; t < 5; ++t) {                                      \
            myq[t].x = cvtpk(S[t][0] * rw, S[t][1] * rw);                                    \
            myq[t].y = cvtpk(S[t][2] * rw, S[t][3] * rw);                                    \
        }                                                                                    \
        uint4 A[6];                                                                          \
        _Pragma("unroll") for (int t = 0; t < 5; ++t) {                                      \
            unsigned px = __shfl_xor((int)myq[t].x, 16);                                     \
            unsigned py = __shfl_xor((int)myq[t].y, 16);                                     \
            if (q & 1) A[t] = uint4{px, py, myq[t].x, myq[t].y};                             \
            else       A[t] = uint4{myq[t].x, myq[t].y, px, py};                             \
        }                                                                                    \
        A[5] = uint4{0u, 0u, 0u, 0u};                                                        \
        const unsigned short* Vs = &lds[12800 + (G) * 6400];                                 \
        _Pragma("unroll") for (int kk = 0; kk < 3; ++kk) {                                   \
            uint4 own = (q >> 1) ? A[2 * kk + 1] : A[2 * kk];                                \
            uint4 snd = (q >> 1) ? A[2 * kk] : A[2 * kk + 1];                                \
            uint4 rcv;                                                                       \
            rcv.x = __shfl_xor((int)snd.x, 32);                                              \
            rcv.y = __shfl_xor((int)snd.y, 32);                                              \
            rcv.z = __shfl_xor((int)snd.z, 32);                                              \
            rcv.w = __shfl_xor((int)snd.w, 32);                                              \
            uint4 fr = (q == 1 || q == 2) ? rcv : own;                                       \
            bf16x8 pa = __builtin_bit_cast(bf16x8, fr);                                      \
            __builtin_amdgcn_s_setprio(1);                                                   \
            _Pragma("unroll") for (int t = 0; t < 5; ++t) {                                  \
                bf16x8 bv;                                                                   \
                if (kk < 2 || q < 2)                                                         \
                    bv = *(const bf16x8*)&Vs[(t * 16 + l15) * 80 + kk * 32 + q * 8];         \
                else bv = bf16x8{};                                                          \
                o[t] = mfma16(pa, bv, o[t]);                                                 \
            }                                                                                \
            __builtin_amdgcn_s_setprio(0);                                                   \
        }                                                                                    \
    }

#define STORE_O(RG)                                                                          \
    {                                                                                        \
        _Pragma("unroll") for (int t = 0; t < 5; ++t)                                        \
            _Pragma("unroll") for (int i = 0; i < 4; ++i)                                    \
                obuf[(q * 4 + i) * 88 + t * 16 + l15] = f2bf(o[t][i]);                       \
        asm volatile("s_waitcnt lgkmcnt(0)" ::: "memory");                                   \
        const size_t gbase =                                                                 \
            ((size_t)b * 4096 + s0 + wv * 64 + (RG) * 16) * 640 + h * 80;                    \
        _Pragma("unroll") for (int it = 0; it < 3; ++it) {                                   \
            int c = it * 64 + lane;                                                          \
            if (c < 160) {                                                                   \
                int r = c / 10, c10 = c % 10;                                                \
                *(uint4*)(fused + gbase + (size_t)r * 640 + c10 * 8) =                       \
                    *(const uint4*)&obuf[r * 88 + c10 * 8];                                  \
            }                                                                                \
        }                                                                                    \
        _Pragma("unroll") for (int t = 0; t < 5; ++t) o[t] = f32x4{};                        \
    }

    // ---- 8-stage pipeline over (rg, g): S(next) issued before PROC(cur)
    AQ_LOAD(0);
    SC(0, sA);                      // S(rg0,g0)
    SC(1, sB);  PROC(0, sA);        // stage (0,0)
    AQ_LOAD(1);
    SC(0, sA);  PROC(1, sB);  STORE_O(0);   // stage (0,1)
    SC(1, sB);  PROC(0, sA);        // stage (1,0)
    AQ_LOAD(2);
    SC(0, sA);  PROC(1, sB);  STORE_O(1);   // stage (1,1)
    SC(1, sB);  PROC(0, sA);        // stage (2,0)
    AQ_LOAD(3);
    SC(0, sA);  PROC(1, sB);  STORE_O(2);   // stage (2,1)
    SC(1, sB);  PROC(0, sA);        // stage (3,0)
    PROC(1, sB);  STORE_O(3);       // stage (3,1) — nothing left to issue

#undef AQ_LOAD
#undef SC
#undef PROC
#undef STORE_O
}

// ---------------- launcher ----------------

extern "C" void kernel_launch(void* const* d_in, const int* in_sizes, int n_in,
                              void* d_out, int out_size, void* d_ws, size_t ws_size,
                              hipStream_t stream) {
    const float* hidden = (const float*)d_in[0];
    const float* enc    = (const float*)d_in[1];
    const float* qual   = (const float*)d_in[2];
    const float* Wq     = (const float*)d_in[3];
    const float* Wks    = (const float*)d_in[4];
    const float* Wvs    = (const float*)d_in[5];
    const float* Wkq    = (const float*)d_in[6];
    const float* Wvq    = (const float*)d_in[7];
    const float* Wout   = (const float*)d_in[8];
    const float* fw     = (const float*)d_in[9];
    float* out = (float*)d_out;

    char* ws = (char*)d_ws;
    unsigned short* hid_bf  = (unsigned short*)(ws + 0);          // 83,886,080 B (reused as fused)
    unsigned short* Qb      = (unsigned short*)(ws + 83886080);   // 83,886,080 B
    unsigned short* encp    = (unsigned short*)(ws + 167772160);  // 6,553,600 B
    unsigned short* wq_bt   = (unsigned short*)(ws + 174325760);  // 819,200 B
    unsigned short* wout_bt = (unsigned short*)(ws + 175144960);  // 819,200 B
    unsigned short* wkv_bt  = (unsigned short*)(ws + 175964160);  // 6,553,600 B
    unsigned short* Kg2     = (unsigned short*)(ws + 182517760);  // 3,276,800 B
    unsigned short* Vt2     = (unsigned short*)(ws + 185794560);  // 3,276,800 B
    unsigned short* fused   = hid_bf;  // overlays hid_bf (dead after Q GEMM)

    k_stream<<<dim3(2048), dim3(256), 0, stream>>>(hidden, hid_bf, enc, qual, encp, (uint4*)Kg2);
    k_transpose_w<<<dim3(20, 10, 6), dim3(256), 0, stream>>>(Wq, Wout, Wks, Wvs, Wkq, Wvq,
                                                             wq_bt, wout_bt, wkv_bt);
    gemm_kv<<<dim3(20, 10, 2), dim3(256), 0, stream>>>(encp, wkv_bt, Kg2, Vt2);
    gemm_bt<0, 1><<<dim3(2560), dim3(256), 0, stream>>>(hid_bf, wq_bt, (void*)Qb, 640, 640, 0L, 0L, 0L);
    attn_kernel<<<dim3(8, 8, 16), dim3(512), 0, stream>>>(Qb, Kg2, Vt2, fw, fused);
    gemm_bt<1, 1><<<dim3(2560), dim3(256), 0, stream>>>(fused, wout_bt, (void*)out, 640, 640, 0L, 0L, 0L);
}

// Round 21
// 289.291 us; speedup vs baseline: 1.0989x; 1.0989x over previous
//
#include <hip/hip_runtime.h>

using f32x4  = __attribute__((ext_vector_type(4))) float;
using bf16x8 = __attribute__((ext_vector_type(8))) __bf16;

#define AS1(p) ((__attribute__((address_space(1))) void*)(p))
#define AS3(p) ((__attribute__((address_space(3))) void*)(p))

__device__ __forceinline__ unsigned short f2bf(float f) {
    unsigned u = __float_as_uint(f);
    unsigned r = u + 0x7FFFu + ((u >> 16) & 1u);
    return (unsigned short)(r >> 16);
}

__device__ __forceinline__ unsigned cvtpk(float lo, float hi) {
    unsigned r;
    asm("v_cvt_pk_bf16_f32 %0, %1, %2" : "=v"(r) : "v"(lo), "v"(hi));
    return r;
}

__device__ __forceinline__ f32x4 mfma16(bf16x8 a, bf16x8 b, f32x4 c) {
    return __builtin_amdgcn_mfma_f32_16x16x32_bf16(a, b, c, 0, 0, 0);
}

// ---------------- streaming prep: hidden cvt + enc pad/cvt + KV-buffer zero-fill ----------------
__global__ void k_stream(const float* __restrict__ hidden, unsigned short* __restrict__ hid_bf,
                         const float* __restrict__ enc, const float* __restrict__ qual,
                         unsigned short* __restrict__ encp, uint4* __restrict__ kvzero) {
    const long N_HID = 5242880;               // 41,943,040 / 8
    const long N_ENC = 819200;                // x4 elems
    const long N_Z   = 409600;                // 6,553,600 B / 16
    const long total = N_HID + N_ENC + N_Z;
    long i0 = (long)blockIdx.x * 256 + threadIdx.x;
    long stride = (long)gridDim.x * 256;
    for (long i = i0; i < total; i += stride) {
        if (i < N_HID) {
            long e = i * 8;
            float4 a = *(const float4*)&hidden[e];
            float4 b = *(const float4*)&hidden[e + 4];
            uint4 v;
            v.x = cvtpk(a.x, a.y);
            v.y = cvtpk(a.z, a.w);
            v.z = cvtpk(b.x, b.y);
            v.w = cvtpk(b.z, b.w);
            *(uint4*)&hid_bf[e] = v;
        } else if (i < N_HID + N_ENC) {
            long e = (i - N_HID) * 4;
            int g = (int)(e / (1280L * 1280));
            long rem = e - (long)g * 1280 * 1280;
            int m = (int)(rem / 1280);
            uint2 v = {0u, 0u};
            if (m < 1232) {
                const float* src = (g ? qual : enc) + rem;
                float4 a = *(const float4*)src;
                v.x = f2bf(a.x) | ((unsigned)f2bf(a.y) << 16);
                v.y = f2bf(a.z) | ((unsigned)f2bf(a.w) << 16);
            }
            *(uint2*)&encp[e] = v;
        } else {
            kvzero[i - N_HID - N_ENC] = uint4{0u, 0u, 0u, 0u};
        }
    }
}

// ---------------- LDS-tile weight transpose: coalesced reads AND writes ----------------
__global__ __launch_bounds__(256) void k_transpose_w(
    const float* __restrict__ Wq, const float* __restrict__ Wout,
    const float* __restrict__ Wks, const float* __restrict__ Wvs,
    const float* __restrict__ Wkq, const float* __restrict__ Wvq,
    unsigned short* __restrict__ wq_bt, unsigned short* __restrict__ wout_bt,
    unsigned short* __restrict__ wkv_bt) {
    const int z = blockIdx.z;
    const float* src; unsigned short* dst; int K; int nbase; float scale = 1.0f;
    switch (z) {
        case 0:  src = Wq;  dst = wq_bt;             K = 640;  nbase = 0;
                 scale = 0.11180339887498949f; break;
        case 1:  src = Wout; dst = wout_bt;          K = 640;  nbase = 0;   break;
        case 2:  src = Wks; dst = wkv_bt;            K = 1280; nbase = 0;   break;
        case 3:  src = Wvs; dst = wkv_bt;            K = 1280; nbase = 640; break;
        case 4:  src = Wkq; dst = wkv_bt + 1638400;  K = 1280; nbase = 0;   break;
        default: src = Wvq; dst = wkv_bt + 1638400;  K = 1280; nbase = 640; break;
    }
    const int k0 = blockIdx.x * 64;
    if (k0 >= K) return;
    const int n0 = blockIdx.y * 64;
    __shared__ float t[64][65];
    const int r4 = threadIdx.x >> 6, c = threadIdx.x & 63;
#pragma unroll
    for (int it = 0; it < 16; ++it) {
        int r = r4 + 4 * it;
        t[r][c] = src[(size_t)(k0 + r) * 640 + n0 + c];   // coalesced 256B rows
    }
    __syncthreads();
#pragma unroll
    for (int it = 0; it < 16; ++it) {
        int n = r4 + 4 * it;
        dst[(size_t)(nbase + n0 + n) * K + k0 + c] = f2bf(t[c][n] * scale);  // coalesced 128B rows
    }
}

// ---------------- GEMM: BK=64, single-buffer 2-barrier, XOR-swizzled LDS (R17-proven) ----------------

template <int OUT_F32, int SWZ>
__global__ __launch_bounds__(256) void gemm_bt(
    const unsigned short* __restrict__ A, const unsigned short* __restrict__ Bt,
    void* __restrict__ Cv, int K, int N, long zA, long zB, long zC)
{
    size_t m0; int n0;
    if (SWZ) {
        int i = blockIdx.x;
        int L = (i & 7) * 320 + (i >> 3);   // 2560 blocks, 8 XCDs, 320 per XCD
        n0 = (L % 5) * 128;
        m0 = (size_t)(L / 5) * 128;
    } else {
        m0 = (size_t)blockIdx.x * 128;
        n0 = blockIdx.y * 128;
    }
    const unsigned short* Ab = A + (size_t)blockIdx.z * zA;
    const unsigned short* Bb = Bt + (size_t)blockIdx.z * zB;
    __shared__ __attribute__((aligned(16))) unsigned short As[128 * 64];
    __shared__ __attribute__((aligned(16))) unsigned short Bs[128 * 64];
    const int tid = threadIdx.x, lane = tid & 63, wv = tid >> 6;
    const int wm = wv >> 1, wn = wv & 1;
    const int srow = lane >> 3;
    const int scol = ((lane & 7) ^ srow) * 8;
    f32x4 acc[4][4] = {};
    for (int k0 = 0; k0 < K; k0 += 64) {
        for (int c = wv; c < 16; c += 4) {
            __builtin_amdgcn_global_load_lds(AS1(Ab + (m0 + c * 8 + srow) * K + k0 + scol),
                                             AS3(&As[c * 512]), 16, 0, 0);
            __builtin_amdgcn_global_load_lds(AS1(Bb + ((size_t)(n0 + c * 8 + srow)) * K + k0 + scol),
                                             AS3(&Bs[c * 512]), 16, 0, 0);
        }
        asm volatile("s_waitcnt vmcnt(0)" ::: "memory");
        __syncthreads();
        const int q = lane >> 4, l15 = lane & 15;
#pragma unroll
        for (int kk = 0; kk < 2; ++kk) {
            bf16x8 a[4], b[4];
#pragma unroll
            for (int i = 0; i < 4; ++i) {
                int ra = wm * 64 + i * 16 + l15;
                int rb = wn * 64 + i * 16 + l15;
                a[i] = *(const bf16x8*)&As[ra * 64 + (((kk * 4 + q) ^ (ra & 7)) * 8)];
                b[i] = *(const bf16x8*)&Bs[rb * 64 + (((kk * 4 + q) ^ (rb & 7)) * 8)];
            }
#pragma unroll
            for (int mi = 0; mi < 4; ++mi)
#pragma unroll
                for (int ni = 0; ni < 4; ++ni)
                    acc[mi][ni] = mfma16(a[mi], b[ni], acc[mi][ni]);
        }
        __syncthreads();
    }
#pragma unroll
    for (int mi = 0; mi < 4; ++mi) {
#pragma unroll
        for (int ni = 0; ni < 4; ++ni) {
            size_t row = m0 + wm * 64 + mi * 16 + ((lane >> 4) * 4);
            int col = n0 + wn * 64 + ni * 16 + (lane & 15);
#pragma unroll
            for (int i = 0; i < 4; ++i) {
                float v = acc[mi][ni][i];
                if (OUT_F32)
                    ((float*)Cv + (size_t)blockIdx.z * zC)[(row + i) * N + col] = v;
                else
                    ((unsigned short*)Cv + (size_t)blockIdx.z * zC)[(row + i) * N + col] = f2bf(v);
            }
        }
    }
}

// ---------------- fused dispatch: Q-GEMM (2560 blocks) + KV-GEMM w/ scatter (400 blocks) ----------------
// Block-uniform branch; LDS union = 32 KB. KV blocks fill CUs alongside the Q-GEMM wave
// instead of serializing as a separate dispatch.
__global__ __launch_bounds__(256) void gemm_qkv(
    const unsigned short* __restrict__ hid, const unsigned short* __restrict__ wqbt,
    unsigned short* __restrict__ Qb,
    const unsigned short* __restrict__ encp, const unsigned short* __restrict__ wkvbt,
    unsigned short* __restrict__ Kg2, unsigned short* __restrict__ Vt2)
{
    __shared__ __attribute__((aligned(16))) unsigned short As[128 * 64];
    __shared__ __attribute__((aligned(16))) unsigned short Bs[128 * 64];
    const int tid = threadIdx.x, lane = tid & 63, wv = tid >> 6;

    if (blockIdx.x < 2560) {
        // ---------- Q-GEMM path: C[65536][640] bf16 = hid * wqbt^T, BK=64 single-buffer ----------
        int L = ((int)blockIdx.x & 7) * 320 + ((int)blockIdx.x >> 3);
        const int n0 = (L % 5) * 128;
        const size_t m0 = (size_t)(L / 5) * 128;
        const int wm = wv >> 1, wn = wv & 1;
        const int srow = lane >> 3;
        const int scol = ((lane & 7) ^ srow) * 8;
        f32x4 acc[4][4] = {};
        for (int k0 = 0; k0 < 640; k0 += 64) {
            for (int c = wv; c < 16; c += 4) {
                __builtin_amdgcn_global_load_lds(AS1(hid + (m0 + c * 8 + srow) * 640 + k0 + scol),
                                                 AS3(&As[c * 512]), 16, 0, 0);
                __builtin_amdgcn_global_load_lds(AS1(wqbt + ((size_t)(n0 + c * 8 + srow)) * 640 + k0 + scol),
                                                 AS3(&Bs[c * 512]), 16, 0, 0);
            }
            asm volatile("s_waitcnt vmcnt(0)" ::: "memory");
            __syncthreads();
            const int q = lane >> 4, l15 = lane & 15;
#pragma unroll
            for (int kk = 0; kk < 2; ++kk) {
                bf16x8 a[4], b[4];
#pragma unroll
                for (int i = 0; i < 4; ++i) {
                    int ra = wm * 64 + i * 16 + l15;
                    int rb = wn * 64 + i * 16 + l15;
                    a[i] = *(const bf16x8*)&As[ra * 64 + (((kk * 4 + q) ^ (ra & 7)) * 8)];
                    b[i] = *(const bf16x8*)&Bs[rb * 64 + (((kk * 4 + q) ^ (rb & 7)) * 8)];
                }
#pragma unroll
                for (int mi = 0; mi < 4; ++mi)
#pragma unroll
                    for (int ni = 0; ni < 4; ++ni)
                        acc[mi][ni] = mfma16(a[mi], b[ni], acc[mi][ni]);
            }
            __syncthreads();
        }
#pragma unroll
        for (int mi = 0; mi < 4; ++mi) {
#pragma unroll
            for (int ni = 0; ni < 4; ++ni) {
                size_t row = m0 + wm * 64 + mi * 16 + ((lane >> 4) * 4);
                int col = n0 + wn * 64 + ni * 16 + (lane & 15);
#pragma unroll
                for (int i = 0; i < 4; ++i)
                    Qb[(row + i) * 640 + col] = f2bf(acc[mi][ni][i]);
            }
        }
    } else {
        // ---------- KV-GEMM path: 400 blocks (20 x 10 x 2), BK=32, fused scatter ----------
        int idx = (int)blockIdx.x - 2560;
        const int bx = idx % 20;
        const int by = (idx / 20) % 10;
        const int g  = idx / 200;
        const size_t m0 = (size_t)bx * 64;
        const int n0 = by * 128;
        const unsigned short* Ab = encp + (size_t)g * 1638400;
        const unsigned short* Bb = wkvbt + (size_t)g * 1638400;
        const int srow = lane >> 2;
        const int scol = ((lane & 3) ^ (srow & 3)) * 8;
        f32x4 acc[4][2] = {};
        for (int k0 = 0; k0 < 1280; k0 += 32) {
            {
                int c = wv;
                __builtin_amdgcn_global_load_lds(AS1(Ab + (m0 + c * 16 + srow) * 1280 + k0 + scol),
                                                 AS3(&As[c * 512]), 16, 0, 0);
            }
            for (int c = wv; c < 8; c += 4)
                __builtin_amdgcn_global_load_lds(AS1(Bb + ((size_t)(n0 + c * 16 + srow)) * 1280 + k0 + scol),
                                                 AS3(&Bs[c * 512]), 16, 0, 0);
            asm volatile("s_waitcnt vmcnt(0)" ::: "memory");
            __syncthreads();
            const int q = lane >> 4, l15 = lane & 15;
            bf16x8 a[4], b[2];
#pragma unroll
            for (int i = 0; i < 4; ++i) {
                int ra = i * 16 + l15;
                a[i] = *(const bf16x8*)&As[ra * 32 + ((q ^ (ra & 3)) * 8)];
            }
#pragma unroll
            for (int j = 0; j < 2; ++j) {
                int rb = wv * 32 + j * 16 + l15;
                b[j] = *(const bf16x8*)&Bs[rb * 32 + ((q ^ (rb & 3)) * 8)];
            }
#pragma unroll
            for (int mi = 0; mi < 4; ++mi)
#pragma unroll
                for (int ni = 0; ni < 2; ++ni)
                    acc[mi][ni] = mfma16(a[mi], b[ni], acc[mi][ni]);
            __syncthreads();
        }
#pragma unroll
        for (int mi = 0; mi < 4; ++mi) {
#pragma unroll
            for (int ni = 0; ni < 2; ++ni) {
                int col = n0 + wv * 32 + ni * 16 + (lane & 15);
#pragma unroll
                for (int i = 0; i < 4; ++i) {
                    int row = (int)m0 + mi * 16 + ((lane >> 4) * 4) + i;
                    if (row < 1232) {
                        int b2 = row / 77, l = row - b2 * 77;
                        unsigned short val = f2bf(acc[mi][ni][i]);
                        if (col < 640) {
                            int h = col / 80, d = col - h * 80;
                            Kg2[(((size_t)g * 16 + b2) * 8 + h) * 6400 + l * 80 + d] = val;
                        } else {
                            int c2 = col - 640;
                            int h = c2 / 80, d = c2 - h * 80;
                            Vt2[(((size_t)g * 16 + b2) * 8 + h) * 6400 + d * 80 + l] = val;
                        }
                    }
                }
            }
        }
    }
}

// ---------------- fused dual attention: software-pipelined S-cluster lookahead ----------------
__global__ __launch_bounds__(512, 4) void attn_kernel(
    const unsigned short* __restrict__ Q,    // [16][4096][640] bf16 (pre-scaled via Wq)
    const unsigned short* __restrict__ Kg2,  // [2][16][8][80][80]
    const unsigned short* __restrict__ Vt2,  // [2][16][8][80][80]
    const float* __restrict__ fw,            // [2]
    unsigned short* __restrict__ fused)      // [16][4096][640] bf16
{
    const int b = blockIdx.z, h = blockIdx.y;
    const int s0 = blockIdx.x * 512;
    __shared__ __attribute__((aligned(16))) unsigned short lds[25600 + 8 * 1408];
    const int tid = threadIdx.x, lane = tid & 63, wv = tid >> 6;
    const int l15 = lane & 15, q = lane >> 4;

    // ---- stage K/V (4 slabs x 800 chunks of 16B), LDS linear
    {
        const unsigned short* sK0 = Kg2 + (size_t)(b * 8 + h) * 6400;
        const unsigned short* sK1 = Kg2 + (size_t)((16 + b) * 8 + h) * 6400;
        const unsigned short* sV0 = Vt2 + (size_t)(b * 8 + h) * 6400;
        const unsigned short* sV1 = Vt2 + (size_t)((16 + b) * 8 + h) * 6400;
#pragma unroll
        for (int it = 0; it < 7; ++it) {
            int chunk = it * 512 + tid;
            if (chunk < 3200) {
                const unsigned short* src = sK0 + (size_t)chunk * 8;
                if (chunk >= 800)  src = sK1 + (size_t)(chunk - 800) * 8;
                if (chunk >= 1600) src = sV0 + (size_t)(chunk - 1600) * 8;
                if (chunk >= 2400) src = sV1 + (size_t)(chunk - 2400) * 8;
                __builtin_amdgcn_global_load_lds(AS1(src), AS3(&lds[(it * 512 + wv * 64) * 8]),
                                                 16, 0, 0);
            }
        }
    }
    asm volatile("s_waitcnt vmcnt(0)" ::: "memory");
    __syncthreads();

    float f0 = fw[0], f1 = fw[1];
    float fm = fmaxf(f0, f1);
    float e0 = __expf(f0 - fm), e1 = __expf(f1 - fm);
    float w0 = e0 / (e0 + e1), w1 = e1 / (e0 + e1);

    unsigned short* obuf = &lds[25600 + wv * 1408];   // per-wave [16][88]

    bf16x8 aq[3];
    f32x4 sA[5], sB[5], o[5];
#pragma unroll
    for (int t = 0; t < 5; ++t) o[t] = f32x4{};

#define AQ_LOAD(RG)                                                                          \
    {                                                                                        \
        const unsigned short* qrow =                                                         \
            Q + ((size_t)b * 4096 + s0 + wv * 64 + (RG) * 16 + l15) * 640 + h * 80;          \
        aq[0] = *(const bf16x8*)(qrow + q * 8);                                              \
        aq[1] = *(const bf16x8*)(qrow + 32 + q * 8);                                         \
        if (q < 2) aq[2] = *(const bf16x8*)(qrow + 64 + q * 8);                              \
        else       aq[2] = bf16x8{};                                                         \
    }

#define SC(G, S)                                                                             \
    {                                                                                        \
        const unsigned short* Ks = &lds[(G) * 6400];                                         \
        _Pragma("unroll") for (int t = 0; t < 5; ++t) S[t] = f32x4{};                        \
        __builtin_amdgcn_s_setprio(1);                                                       \
        _Pragma("unroll") for (int t = 0; t < 5; ++t)                                        \
            _Pragma("unroll") for (int kk = 0; kk < 3; ++kk) {                               \
                bf16x8 ak;                                                                   \
                if (kk < 2 || q < 2)                                                         \
                    ak = *(const bf16x8*)&Ks[(t * 16 + l15) * 80 + kk * 32 + q * 8];         \
                else ak = bf16x8{};                                                          \
                S[t] = mfma16(ak, aq[kk], S[t]);                                             \
            }                                                                                \
        __builtin_amdgcn_s_setprio(0);                                                       \
    }

#define PROC(G, S)                                                                           \
    {                                                                                        \
        float sum = 0.f;                                                                     \
        _Pragma("unroll") for (int t = 0; t < 4; ++t)                                        \
            _Pragma("unroll") for (int i = 0; i < 4; ++i) {                                  \
                S[t][i] = __expf(S[t][i]); sum += S[t][i];                                   \
            }                                                                                \
        _Pragma("unroll") for (int i = 0; i < 4; ++i) {                                      \
            S[4][i] = (q * 4 + i < 13) ? __expf(S[4][i]) : 0.f;                              \
            sum += S[4][i];                                                                  \
        }                                                                                    \
        sum += __shfl_xor(sum, 16);                                                          \
        sum += __shfl_xor(sum, 32);                                                          \
        float rw = ((G) ? w1 : w0) / sum;                                                    \
        uint2 myq[5];                                                                        \
        _Pragma("unroll") for (int t = 0; t < 5; ++t) {                                      \
            myq[t].x = cvtpk(S[t][0] * rw, S[t][1] * rw);                                    \
            myq[t].y = cvtpk(S[t][2] * rw, S[t][3] * rw);                                    \
        }                                                                                    \
        uint4 A[6];                                                                          \
        _Pragma("unroll") for (int t = 0; t < 5; ++t) {                                      \
            unsigned px = __shfl_xor((int)myq[t].x, 16);                                     \
            unsigned py = __shfl_xor((int)myq[t].y, 16);                                     \
            if (q & 1) A[t] = uint4{px, py, myq[t].x, myq[t].y};                             \
            else       A[t] = uint4{myq[t].x, myq[t].y, px, py};                             \
        }                                                                                    \
        A[5] = uint4{0u, 0u, 0u, 0u};                                                        \
        const unsigned short* Vs = &lds[12800 + (G) * 6400];                                 \
        _Pragma("unroll") for (int kk = 0; kk < 3; ++kk) {                                   \
            uint4 own = (q >> 1) ? A[2 * kk + 1] : A[2 * kk];                                \
            uint4 snd = (q >> 1) ? A[2 * kk] : A[2 * kk + 1];                                \
            uint4 rcv;                                                                       \
            rcv.x = __shfl_xor((int)snd.x, 32);                                              \
            rcv.y = __shfl_xor((int)snd.y, 32);                                              \
            rcv.z = __shfl_xor((int)snd.z, 32);                                              \
            rcv.w = __shfl_xor((int)snd.w, 32);                                              \
            uint4 fr = (q == 1 || q == 2) ? rcv : own;                                       \
            bf16x8 pa = __builtin_bit_cast(bf16x8, fr);                                      \
            __builtin_amdgcn_s_setprio(1);                                                   \
            _Pragma("unroll") for (int t = 0; t < 5; ++t) {                                  \
                bf16x8 bv;                                                                   \
                if (kk < 2 || q < 2)                                                         \
                    bv = *(const bf16x8*)&Vs[(t * 16 + l15) * 80 + kk * 32 + q * 8];         \
                else bv = bf16x8{};                                                          \
                o[t] = mfma16(pa, bv, o[t]);                                                 \
            }                                                                                \
            __builtin_amdgcn_s_setprio(0);                                                   \
        }                                                                                    \
    }

#define STORE_O(RG)                                                                          \
    {                                                                                        \
        _Pragma("unroll") for (int t = 0; t < 5; ++t)                                        \
            _Pragma("unroll") for (int i = 0; i < 4; ++i)                                    \
                obuf[(q * 4 + i) * 88 + t * 16 + l15] = f2bf(o[t][i]);                       \
        asm volatile("s_waitcnt lgkmcnt(0)" ::: "memory");                                   \
        const size_t gbase =                                                                 \
            ((size_t)b * 4096 + s0 + wv * 64 + (RG) * 16) * 640 + h * 80;                    \
        _Pragma("unroll") for (int it = 0; it < 3; ++it) {                                   \
            int c = it * 64 + lane;                                                          \
            if (c < 160) {                                                                   \
                int r = c / 10, c10 = c % 10;                                                \
                *(uint4*)(fused + gbase + (size_t)r * 640 + c10 * 8) =                       \
                    *(const uint4*)&obuf[r * 88 + c10 * 8];                                  \
            }                                                                                \
        }                                                                                    \
        _Pragma("unroll") for (int t = 0; t < 5; ++t) o[t] = f32x4{};                        \
    }

    // ---- 8-stage pipeline over (rg, g): S(next) issued before PROC(cur)
    AQ_LOAD(0);
    SC(0, sA);                      // S(rg0,g0)
    SC(1, sB);  PROC(0, sA);        // stage (0,0)
    AQ_LOAD(1);
    SC(0, sA);  PROC(1, sB);  STORE_O(0);   // stage (0,1)
    SC(1, sB);  PROC(0, sA);        // stage (1,0)
    AQ_LOAD(2);
    SC(0, sA);  PROC(1, sB);  STORE_O(1);   // stage (1,1)
    SC(1, sB);  PROC(0, sA);        // stage (2,0)
    AQ_LOAD(3);
    SC(0, sA);  PROC(1, sB);  STORE_O(2);   // stage (2,1)
    SC(1, sB);  PROC(0, sA);        // stage (3,0)
    PROC(1, sB);  STORE_O(3);       // stage (3,1) — nothing left to issue

#undef AQ_LOAD
#undef SC
#undef PROC
#undef STORE_O
}

// ---------------- launcher ----------------

extern "C" void kernel_launch(void* const* d_in, const int* in_sizes, int n_in,
                              void* d_out, int out_size, void* d_ws, size_t ws_size,
                              hipStream_t stream) {
    const float* hidden = (const float*)d_in[0];
    const float* enc    = (const float*)d_in[1];
    const float* qual   = (const float*)d_in[2];
    const float* Wq     = (const float*)d_in[3];
    const float* Wks    = (const float*)d_in[4];
    const float* Wvs    = (const float*)d_in[5];
    const float* Wkq    = (const float*)d_in[6];
    const float* Wvq    = (const float*)d_in[7];
    const float* Wout   = (const float*)d_in[8];
    const float* fw     = (const float*)d_in[9];
    float* out = (float*)d_out;

    char* ws = (char*)d_ws;
    unsigned short* hid_bf  = (unsigned short*)(ws + 0);          // 83,886,080 B (reused as fused)
    unsigned short* Qb      = (unsigned short*)(ws + 83886080);   // 83,886,080 B
    unsigned short* encp    = (unsigned short*)(ws + 167772160);  // 6,553,600 B
    unsigned short* wq_bt   = (unsigned short*)(ws + 174325760);  // 819,200 B
    unsigned short* wout_bt = (unsigned short*)(ws + 175144960);  // 819,200 B
    unsigned short* wkv_bt  = (unsigned short*)(ws + 175964160);  // 6,553,600 B
    unsigned short* Kg2     = (unsigned short*)(ws + 182517760);  // 3,276,800 B
    unsigned short* Vt2     = (unsigned short*)(ws + 185794560);  // 3,276,800 B
    unsigned short* fused   = hid_bf;  // overlays hid_bf (dead after Q GEMM)

    k_stream<<<dim3(2048), dim3(256), 0, stream>>>(hidden, hid_bf, enc, qual, encp, (uint4*)Kg2);
    k_transpose_w<<<dim3(20, 10, 6), dim3(256), 0, stream>>>(Wq, Wout, Wks, Wvs, Wkq, Wvq,
                                                             wq_bt, wout_bt, wkv_bt);
    gemm_qkv<<<dim3(2960), dim3(256), 0, stream>>>(hid_bf, wq_bt, Qb, encp, wkv_bt, Kg2, Vt2);
    attn_kernel<<<dim3(8, 8, 16), dim3(512), 0, stream>>>(Qb, Kg2, Vt2, fw, fused);
    gemm_bt<1, 1><<<dim3(2560), dim3(256), 0, stream>>>(fused, wout_bt, (void*)out, 640, 640, 0L, 0L, 0L);
}

// Round 22
// 276.054 us; speedup vs baseline: 1.1515x; 1.0479x over previous
//
#include <hip/hip_runtime.h>

using f32x4  = __attribute__((ext_vector_type(4))) float;
using bf16x8 = __attribute__((ext_vector_type(8))) __bf16;

#define AS1(p) ((__attribute__((address_space(1))) void*)(p))
#define AS3(p) ((__attribute__((address_space(3))) void*)(p))

__device__ __forceinline__ unsigned short f2bf(float f) {
    unsigned u = __float_as_uint(f);
    unsigned r = u + 0x7FFFu + ((u >> 16) & 1u);
    return (unsigned short)(r >> 16);
}

__device__ __forceinline__ unsigned cvtpk(float lo, float hi) {
    unsigned r;
    asm("v_cvt_pk_bf16_f32 %0, %1, %2" : "=v"(r) : "v"(lo), "v"(hi));
    return r;
}

__device__ __forceinline__ f32x4 mfma16(bf16x8 a, bf16x8 b, f32x4 c) {
    return __builtin_amdgcn_mfma_f32_16x16x32_bf16(a, b, c, 0, 0, 0);
}

// ---------------- merged prep: weight transposes (blocks 0-1199) + streaming (1200-3247) ----------------
__global__ __launch_bounds__(256) void k_prep2(
    const float* __restrict__ hidden, unsigned short* __restrict__ hid_bf,
    const float* __restrict__ enc, const float* __restrict__ qual,
    unsigned short* __restrict__ encp, uint4* __restrict__ kvzero,
    const float* __restrict__ Wq, const float* __restrict__ Wout,
    const float* __restrict__ Wks, const float* __restrict__ Wvs,
    const float* __restrict__ Wkq, const float* __restrict__ Wvq,
    unsigned short* __restrict__ wq_bt, unsigned short* __restrict__ wout_bt,
    unsigned short* __restrict__ wkv_bt)
{
    __shared__ float t[64][65];
    if (blockIdx.x < 1200) {
        // ---- transpose path: idx -> (z, bx, by); src f32 [K][640] -> dst bf16 [.][K]
        int idx = blockIdx.x;
        const int z = idx / 200;
        const int bx = idx % 20;
        const int by = (idx / 20) % 10;
        const float* src; unsigned short* dst; int K; int nbase; float scale = 1.0f;
        switch (z) {
            case 0:  src = Wq;  dst = wq_bt;             K = 640;  nbase = 0;
                     scale = 0.11180339887498949f; break;
            case 1:  src = Wout; dst = wout_bt;          K = 640;  nbase = 0;   break;
            case 2:  src = Wks; dst = wkv_bt;            K = 1280; nbase = 0;   break;
            case 3:  src = Wvs; dst = wkv_bt;            K = 1280; nbase = 640; break;
            case 4:  src = Wkq; dst = wkv_bt + 1638400;  K = 1280; nbase = 0;   break;
            default: src = Wvq; dst = wkv_bt + 1638400;  K = 1280; nbase = 640; break;
        }
        const int k0 = bx * 64;
        if (k0 >= K) return;
        const int n0 = by * 64;
        const int r4 = threadIdx.x >> 6, c = threadIdx.x & 63;
#pragma unroll
        for (int it = 0; it < 16; ++it) {
            int r = r4 + 4 * it;
            t[r][c] = src[(size_t)(k0 + r) * 640 + n0 + c];
        }
        __syncthreads();
#pragma unroll
        for (int it = 0; it < 16; ++it) {
            int n = r4 + 4 * it;
            dst[(size_t)(nbase + n0 + n) * K + k0 + c] = f2bf(t[c][n] * scale);
        }
    } else {
        // ---- streaming path: hidden cvt + enc pad/cvt + KV zero-fill
        const long N_HID = 5242880;
        const long N_ENC = 819200;
        const long N_Z   = 409600;
        const long total = N_HID + N_ENC + N_Z;
        long i0 = (long)(blockIdx.x - 1200) * 256 + threadIdx.x;
        long stride = 2048L * 256;
        for (long i = i0; i < total; i += stride) {
            if (i < N_HID) {
                long e = i * 8;
                float4 a = *(const float4*)&hidden[e];
                float4 b = *(const float4*)&hidden[e + 4];
                uint4 v;
                v.x = cvtpk(a.x, a.y);
                v.y = cvtpk(a.z, a.w);
                v.z = cvtpk(b.x, b.y);
                v.w = cvtpk(b.z, b.w);
                *(uint4*)&hid_bf[e] = v;
            } else if (i < N_HID + N_ENC) {
                long e = (i - N_HID) * 4;
                int g = (int)(e / (1280L * 1280));
                long rem = e - (long)g * 1280 * 1280;
                int m = (int)(rem / 1280);
                uint2 v = {0u, 0u};
                if (m < 1232) {
                    const float* src = (g ? qual : enc) + rem;
                    float4 a = *(const float4*)src;
                    v.x = f2bf(a.x) | ((unsigned)f2bf(a.y) << 16);
                    v.y = f2bf(a.z) | ((unsigned)f2bf(a.w) << 16);
                }
                *(uint2*)&encp[e] = v;
            } else {
                kvzero[i - N_HID - N_ENC] = uint4{0u, 0u, 0u, 0u};
            }
        }
    }
}

// ---------------- GEMM: BK=64, single-buffer 2-barrier, XOR-swizzled LDS (R17-proven) ----------------

template <int OUT_F32, int SWZ>
__global__ __launch_bounds__(256) void gemm_bt(
    const unsigned short* __restrict__ A, const unsigned short* __restrict__ Bt,
    void* __restrict__ Cv, int K, int N, long zA, long zB, long zC)
{
    size_t m0; int n0;
    if (SWZ) {
        int i = blockIdx.x;
        int L = (i & 7) * 320 + (i >> 3);   // 2560 blocks, 8 XCDs, 320 per XCD
        n0 = (L % 5) * 128;
        m0 = (size_t)(L / 5) * 128;
    } else {
        m0 = (size_t)blockIdx.x * 128;
        n0 = blockIdx.y * 128;
    }
    const unsigned short* Ab = A + (size_t)blockIdx.z * zA;
    const unsigned short* Bb = Bt + (size_t)blockIdx.z * zB;
    __shared__ __attribute__((aligned(16))) unsigned short As[128 * 64];
    __shared__ __attribute__((aligned(16))) unsigned short Bs[128 * 64];
    const int tid = threadIdx.x, lane = tid & 63, wv = tid >> 6;
    const int wm = wv >> 1, wn = wv & 1;
    const int srow = lane >> 3;
    const int scol = ((lane & 7) ^ srow) * 8;
    f32x4 acc[4][4] = {};
    for (int k0 = 0; k0 < K; k0 += 64) {
        for (int c = wv; c < 16; c += 4) {
            __builtin_amdgcn_global_load_lds(AS1(Ab + (m0 + c * 8 + srow) * K + k0 + scol),
                                             AS3(&As[c * 512]), 16, 0, 0);
            __builtin_amdgcn_global_load_lds(AS1(Bb + ((size_t)(n0 + c * 8 + srow)) * K + k0 + scol),
                                             AS3(&Bs[c * 512]), 16, 0, 0);
        }
        asm volatile("s_waitcnt vmcnt(0)" ::: "memory");
        __syncthreads();
        const int q = lane >> 4, l15 = lane & 15;
#pragma unroll
        for (int kk = 0; kk < 2; ++kk) {
            bf16x8 a[4], b[4];
#pragma unroll
            for (int i = 0; i < 4; ++i) {
                int ra = wm * 64 + i * 16 + l15;
                int rb = wn * 64 + i * 16 + l15;
                a[i] = *(const bf16x8*)&As[ra * 64 + (((kk * 4 + q) ^ (ra & 7)) * 8)];
                b[i] = *(const bf16x8*)&Bs[rb * 64 + (((kk * 4 + q) ^ (rb & 7)) * 8)];
            }
#pragma unroll
            for (int mi = 0; mi < 4; ++mi)
#pragma unroll
                for (int ni = 0; ni < 4; ++ni)
                    acc[mi][ni] = mfma16(a[mi], b[ni], acc[mi][ni]);
        }
        __syncthreads();
    }
#pragma unroll
    for (int mi = 0; mi < 4; ++mi) {
#pragma unroll
        for (int ni = 0; ni < 4; ++ni) {
            size_t row = m0 + wm * 64 + mi * 16 + ((lane >> 4) * 4);
            int col = n0 + wn * 64 + ni * 16 + (lane & 15);
#pragma unroll
            for (int i = 0; i < 4; ++i) {
                float v = acc[mi][ni][i];
                if (OUT_F32)
                    ((float*)Cv + (size_t)blockIdx.z * zC)[(row + i) * N + col] = v;
                else
                    ((unsigned short*)Cv + (size_t)blockIdx.z * zC)[(row + i) * N + col] = f2bf(v);
            }
        }
    }
}

// ---------------- fused dispatch: Q-GEMM (2560 blocks) + KV-GEMM BK=64 w/ scatter (400 blocks) ----------------
__global__ __launch_bounds__(256) void gemm_qkv(
    const unsigned short* __restrict__ hid, const unsigned short* __restrict__ wqbt,
    unsigned short* __restrict__ Qb,
    const unsigned short* __restrict__ encp, const unsigned short* __restrict__ wkvbt,
    unsigned short* __restrict__ Kg2, unsigned short* __restrict__ Vt2)
{
    __shared__ __attribute__((aligned(16))) unsigned short As[128 * 64];
    __shared__ __attribute__((aligned(16))) unsigned short Bs[128 * 64];
    const int tid = threadIdx.x, lane = tid & 63, wv = tid >> 6;

    if (blockIdx.x < 2560) {
        // ---------- Q-GEMM path: BK=64 single-buffer ----------
        int L = ((int)blockIdx.x & 7) * 320 + ((int)blockIdx.x >> 3);
        const int n0 = (L % 5) * 128;
        const size_t m0 = (size_t)(L / 5) * 128;
        const int wm = wv >> 1, wn = wv & 1;
        const int srow = lane >> 3;
        const int scol = ((lane & 7) ^ srow) * 8;
        f32x4 acc[4][4] = {};
        for (int k0 = 0; k0 < 640; k0 += 64) {
            for (int c = wv; c < 16; c += 4) {
                __builtin_amdgcn_global_load_lds(AS1(hid + (m0 + c * 8 + srow) * 640 + k0 + scol),
                                                 AS3(&As[c * 512]), 16, 0, 0);
                __builtin_amdgcn_global_load_lds(AS1(wqbt + ((size_t)(n0 + c * 8 + srow)) * 640 + k0 + scol),
                                                 AS3(&Bs[c * 512]), 16, 0, 0);
            }
            asm volatile("s_waitcnt vmcnt(0)" ::: "memory");
            __syncthreads();
            const int q = lane >> 4, l15 = lane & 15;
#pragma unroll
            for (int kk = 0; kk < 2; ++kk) {
                bf16x8 a[4], b[4];
#pragma unroll
                for (int i = 0; i < 4; ++i) {
                    int ra = wm * 64 + i * 16 + l15;
                    int rb = wn * 64 + i * 16 + l15;
                    a[i] = *(const bf16x8*)&As[ra * 64 + (((kk * 4 + q) ^ (ra & 7)) * 8)];
                    b[i] = *(const bf16x8*)&Bs[rb * 64 + (((kk * 4 + q) ^ (rb & 7)) * 8)];
                }
#pragma unroll
                for (int mi = 0; mi < 4; ++mi)
#pragma unroll
                    for (int ni = 0; ni < 4; ++ni)
                        acc[mi][ni] = mfma16(a[mi], b[ni], acc[mi][ni]);
            }
            __syncthreads();
        }
#pragma unroll
        for (int mi = 0; mi < 4; ++mi) {
#pragma unroll
            for (int ni = 0; ni < 4; ++ni) {
                size_t row = m0 + wm * 64 + mi * 16 + ((lane >> 4) * 4);
                int col = n0 + wn * 64 + ni * 16 + (lane & 15);
#pragma unroll
                for (int i = 0; i < 4; ++i)
                    Qb[(row + i) * 640 + col] = f2bf(acc[mi][ni][i]);
            }
        }
    } else {
        // ---------- KV-GEMM path: 64x128 tile, BK=64 (8-slot swizzle, conflict-free), fused scatter ----------
        int idx = (int)blockIdx.x - 2560;
        const int bx = idx % 20;
        const int by = (idx / 20) % 10;
        const int g  = idx / 200;
        const size_t m0 = (size_t)bx * 64;
        const int n0 = by * 128;
        const unsigned short* Ab = encp + (size_t)g * 1638400;
        const unsigned short* Bb = wkvbt + (size_t)g * 1638400;
        const int srow = lane >> 3;
        const int scol = ((lane & 7) ^ srow) * 8;
        f32x4 acc[4][2] = {};
        for (int k0 = 0; k0 < 1280; k0 += 64) {
            for (int c = wv; c < 8; c += 4)   // A: 64 rows = 8 chunks of 8 rows
                __builtin_amdgcn_global_load_lds(AS1(Ab + (m0 + c * 8 + srow) * 1280 + k0 + scol),
                                                 AS3(&As[c * 512]), 16, 0, 0);
            for (int c = wv; c < 16; c += 4)  // B: 128 rows = 16 chunks
                __builtin_amdgcn_global_load_lds(AS1(Bb + ((size_t)(n0 + c * 8 + srow)) * 1280 + k0 + scol),
                                                 AS3(&Bs[c * 512]), 16, 0, 0);
            asm volatile("s_waitcnt vmcnt(0)" ::: "memory");
            __syncthreads();
            const int q = lane >> 4, l15 = lane & 15;
#pragma unroll
            for (int kk = 0; kk < 2; ++kk) {
                bf16x8 a[4], b[2];
#pragma unroll
                for (int i = 0; i < 4; ++i) {
                    int ra = i * 16 + l15;
                    a[i] = *(const bf16x8*)&As[ra * 64 + (((kk * 4 + q) ^ (ra & 7)) * 8)];
                }
#pragma unroll
                for (int j = 0; j < 2; ++j) {
                    int rb = wv * 32 + j * 16 + l15;
                    b[j] = *(const bf16x8*)&Bs[rb * 64 + (((kk * 4 + q) ^ (rb & 7)) * 8)];
                }
#pragma unroll
                for (int mi = 0; mi < 4; ++mi)
#pragma unroll
                    for (int ni = 0; ni < 2; ++ni)
                        acc[mi][ni] = mfma16(a[mi], b[ni], acc[mi][ni]);
            }
            __syncthreads();
        }
#pragma unroll
        for (int mi = 0; mi < 4; ++mi) {
#pragma unroll
            for (int ni = 0; ni < 2; ++ni) {
                int col = n0 + wv * 32 + ni * 16 + (lane & 15);
#pragma unroll
                for (int i = 0; i < 4; ++i) {
                    int row = (int)m0 + mi * 16 + ((lane >> 4) * 4) + i;
                    if (row < 1232) {
                        int b2 = row / 77, l = row - b2 * 77;
                        unsigned short val = f2bf(acc[mi][ni][i]);
                        if (col < 640) {
                            int h = col / 80, d = col - h * 80;
                            Kg2[(((size_t)g * 16 + b2) * 8 + h) * 6400 + l * 80 + d] = val;
                        } else {
                            int c2 = col - 640;
                            int h = c2 / 80, d = c2 - h * 80;
                            Vt2[(((size_t)g * 16 + b2) * 8 + h) * 6400 + d * 80 + l] = val;
                        }
                    }
                }
            }
        }
    }
}

// ---------------- fused dual attention: software-pipelined S-cluster lookahead ----------------
__global__ __launch_bounds__(512, 4) void attn_kernel(
    const unsigned short* __restrict__ Q,    // [16][4096][640] bf16 (pre-scaled via Wq)
    const unsigned short* __restrict__ Kg2,  // [2][16][8][80][80]
    const unsigned short* __restrict__ Vt2,  // [2][16][8][80][80]
    const float* __restrict__ fw,            // [2]
    unsigned short* __restrict__ fused)      // [16][4096][640] bf16
{
    const int b = blockIdx.z, h = blockIdx.y;
    const int s0 = blockIdx.x * 512;
    __shared__ __attribute__((aligned(16))) unsigned short lds[25600 + 8 * 1408];
    const int tid = threadIdx.x, lane = tid & 63, wv = tid >> 6;
    const int l15 = lane & 15, q = lane >> 4;

    // ---- stage K/V (4 slabs x 800 chunks of 16B), LDS linear
    {
        const unsigned short* sK0 = Kg2 + (size_t)(b * 8 + h) * 6400;
        const unsigned short* sK1 = Kg2 + (size_t)((16 + b) * 8 + h) * 6400;
        const unsigned short* sV0 = Vt2 + (size_t)(b * 8 + h) * 6400;
        const unsigned short* sV1 = Vt2 + (size_t)((16 + b) * 8 + h) * 6400;
#pragma unroll
        for (int it = 0; it < 7; ++it) {
            int chunk = it * 512 + tid;
            if (chunk < 3200) {
                const unsigned short* src = sK0 + (size_t)chunk * 8;
                if (chunk >= 800)  src = sK1 + (size_t)(chunk - 800) * 8;
                if (chunk >= 1600) src = sV0 + (size_t)(chunk - 1600) * 8;
                if (chunk >= 2400) src = sV1 + (size_t)(chunk - 2400) * 8;
                __builtin_amdgcn_global_load_lds(AS1(src), AS3(&lds[(it * 512 + wv * 64) * 8]),
                                                 16, 0, 0);
            }
        }
    }
    asm volatile("s_waitcnt vmcnt(0)" ::: "memory");
    __syncthreads();

    float f0 = fw[0], f1 = fw[1];
    float fm = fmaxf(f0, f1);
    float e0 = __expf(f0 - fm), e1 = __expf(f1 - fm);
    float w0 = e0 / (e0 + e1), w1 = e1 / (e0 + e1);

    unsigned short* obuf = &lds[25600 + wv * 1408];   // per-wave [16][88]

    bf16x8 aq[3];
    f32x4 sA[5], sB[5], o[5];
#pragma unroll
    for (int t = 0; t < 5; ++t) o[t] = f32x4{};

#define AQ_LOAD(RG)                                                                          \
    {                                                                                        \
        const unsigned short* qrow =                                                         \
            Q + ((size_t)b * 4096 + s0 + wv * 64 + (RG) * 16 + l15) * 640 + h * 80;          \
        aq[0] = *(const bf16x8*)(qrow + q * 8);                                              \
        aq[1] = *(const bf16x8*)(qrow + 32 + q * 8);                                         \
        if (q < 2) aq[2] = *(const bf16x8*)(qrow + 64 + q * 8);                              \
        else       aq[2] = bf16x8{};                                                         \
    }

#define SC(G, S)                                                                             \
    {                                                                                        \
        const unsigned short* Ks = &lds[(G) * 6400];                                         \
        _Pragma("unroll") for (int t = 0; t < 5; ++t) S[t] = f32x4{};                        \
        __builtin_amdgcn_s_setprio(1);                                                       \
        _Pragma("unroll") for (int t = 0; t < 5; ++t)                                        \
            _Pragma("unroll") for (int kk = 0; kk < 3; ++kk) {                               \
                bf16x8 ak;                                                                   \
                if (kk < 2 || q < 2)                                                         \
                    ak = *(const bf16x8*)&Ks[(t * 16 + l15) * 80 + kk * 32 + q * 8];         \
                else ak = bf16x8{};                                                          \
                S[t] = mfma16(ak, aq[kk], S[t]);                                             \
            }                                                                                \
        __builtin_amdgcn_s_setprio(0);                                                       \
    }

#define PROC(G, S)                                                                           \
    {                                                                                        \
        float sum = 0.f;                                                                     \
        _Pragma("unroll") for (int t = 0; t < 4; ++t)                                        \
            _Pragma("unroll") for (int i = 0; i < 4; ++i) {                                  \
                S[t][i] = __expf(S[t][i]); sum += S[t][i];                                   \
            }                                                                                \
        _Pragma("unroll") for (int i = 0; i < 4; ++i) {                                      \
            S[4][i] = (q * 4 + i < 13) ? __expf(S[4][i]) : 0.f;                              \
            sum += S[4][i];                                                                  \
        }                                                                                    \
        sum += __shfl_xor(sum, 16);                                                          \
        sum += __shfl_xor(sum, 32);                                                          \
        float rw = ((G) ? w1 : w0) / sum;                                                    \
        uint2 myq[5];                                                                        \
        _Pragma("unroll") for (int t = 0; t < 5; ++t) {                                      \
            myq[t].x = cvtpk(S[t][0] * rw, S[t][1] * rw);                                    \
            myq[t].y = cvtpk(S[t][2] * rw, S[t][3] * rw);                                    \
        }                                                                                    \
        uint4 A[6];                                                                          \
        _Pragma("unroll") for (int t = 0; t < 5; ++t) {                                      \
            unsigned px = __shfl_xor((int)myq[t].x, 16);                                     \
            unsigned py = __shfl_xor((int)myq[t].y, 16);                                     \
            if (q & 1) A[t] = uint4{px, py, myq[t].x, myq[t].y};                             \
            else       A[t] = uint4{myq[t].x, myq[t].y, px, py};                             \
        }                                                                                    \
        A[5] = uint4{0u, 0u, 0u, 0u};                                                        \
        const unsigned short* Vs = &lds[12800 + (G) * 6400];                                 \
        _Pragma("unroll") for (int kk = 0; kk < 3; ++kk) {                                   \
            uint4 own = (q >> 1) ? A[2 * kk + 1] : A[2 * kk];                                \
            uint4 snd = (q >> 1) ? A[2 * kk] : A[2 * kk + 1];                                \
            uint4 rcv;                                                                       \
            rcv.x = __shfl_xor((int)snd.x, 32);                                              \
            rcv.y = __shfl_xor((int)snd.y, 32);                                              \
            rcv.z = __shfl_xor((int)snd.z, 32);                                              \
            rcv.w = __shfl_xor((int)snd.w, 32);                                              \
            uint4 fr = (q == 1 || q == 2) ? rcv : own;                                       \
            bf16x8 pa = __builtin_bit_cast(bf16x8, fr);                                      \
            __builtin_amdgcn_s_setprio(1);                                                   \
            _Pragma("unroll") for (int t = 0; t < 5; ++t) {                                  \
                bf16x8 bv;                                                                   \
                if (kk < 2 || q < 2)                                                         \
                    bv = *(const bf16x8*)&Vs[(t * 16 + l15) * 80 + kk * 32 + q * 8];         \
                else bv = bf16x8{};                                                          \
                o[t] = mfma16(pa, bv, o[t]);                                                 \
            }                                                                                \
            __builtin_amdgcn_s_setprio(0);                                                   \
        }                                                                                    \
    }

#define STORE_O(RG)                                                                          \
    {                                                                                        \
        _Pragma("unroll") for (int t = 0; t < 5; ++t)                                        \
            _Pragma("unroll") for (int i = 0; i < 4; ++i)                                    \
                obuf[(q * 4 + i) * 88 + t * 16 + l15] = f2bf(o[t][i]);                       \
        asm volatile("s_waitcnt lgkmcnt(0)" ::: "memory");                                   \
        const size_t gbase =                                                                 \
            ((size_t)b * 4096 + s0 + wv * 64 + (RG) * 16) * 640 + h * 80;                    \
        _Pragma("unroll") for (int it = 0; it < 3; ++it) {                                   \
            int c = it * 64 + lane;                                                          \
            if (c < 160) {                                                                   \
                int r = c / 10, c10 = c % 10;                                                \
                *(uint4*)(fused + gbase + (size_t)r * 640 + c10 * 8) =                       \
                    *(const uint4*)&obuf[r * 88 + c10 * 8];                                  \
            }                                                                                \
        }                                                                                    \
        _Pragma("unroll") for (int t = 0; t < 5; ++t) o[t] = f32x4{};                        \
    }

    // ---- 8-stage pipeline over (rg, g): S(next) issued before PROC(cur)
    AQ_LOAD(0);
    SC(0, sA);                      // S(rg0,g0)
    SC(1, sB);  PROC(0, sA);        // stage (0,0)
    AQ_LOAD(1);
    SC(0, sA);  PROC(1, sB);  STORE_O(0);   // stage (0,1)
    SC(1, sB);  PROC(0, sA);        // stage (1,0)
    AQ_LOAD(2);
    SC(0, sA);  PROC(1, sB);  STORE_O(1);   // stage (1,1)
    SC(1, sB);  PROC(0, sA);        // stage (2,0)
    AQ_LOAD(3);
    SC(0, sA);  PROC(1, sB);  STORE_O(2);   // stage (2,1)
    SC(1, sB);  PROC(0, sA);        // stage (3,0)
    PROC(1, sB);  STORE_O(3);       // stage (3,1) — nothing left to issue

#undef AQ_LOAD
#undef SC
#undef PROC
#undef STORE_O
}

// ---------------- launcher ----------------

extern "C" void kernel_launch(void* const* d_in, const int* in_sizes, int n_in,
                              void* d_out, int out_size, void* d_ws, size_t ws_size,
                              hipStream_t stream) {
    const float* hidden = (const float*)d_in[0];
    const float* enc    = (const float*)d_in[1];
    const float* qual   = (const float*)d_in[2];
    const float* Wq     = (const float*)d_in[3];
    const float* Wks    = (const float*)d_in[4];
    const float* Wvs    = (const float*)d_in[5];
    const float* Wkq    = (const float*)d_in[6];
    const float* Wvq    = (const float*)d_in[7];
    const float* Wout   = (const float*)d_in[8];
    const float* fw     = (const float*)d_in[9];
    float* out = (float*)d_out;

    char* ws = (char*)d_ws;
    unsigned short* hid_bf  = (unsigned short*)(ws + 0);          // 83,886,080 B (reused as fused)
    unsigned short* Qb      = (unsigned short*)(ws + 83886080);   // 83,886,080 B
    unsigned short* encp    = (unsigned short*)(ws + 167772160);  // 6,553,600 B
    unsigned short* wq_bt   = (unsigned short*)(ws + 174325760);  // 819,200 B
    unsigned short* wout_bt = (unsigned short*)(ws + 175144960);  // 819,200 B
    unsigned short* wkv_bt  = (unsigned short*)(ws + 175964160);  // 6,553,600 B
    unsigned short* Kg2     = (unsigned short*)(ws + 182517760);  // 3,276,800 B
    unsigned short* Vt2     = (unsigned short*)(ws + 185794560);  // 3,276,800 B
    unsigned short* fused   = hid_bf;  // overlays hid_bf (dead after Q GEMM)

    k_prep2<<<dim3(3248), dim3(256), 0, stream>>>(hidden, hid_bf, enc, qual, encp, (uint4*)Kg2,
                                                  Wq, Wout, Wks, Wvs, Wkq, Wvq,
                                                  wq_bt, wout_bt, wkv_bt);
    gemm_qkv<<<dim3(2960), dim3(256), 0, stream>>>(hid_bf, wq_bt, Qb, encp, wkv_bt, Kg2, Vt2);
    attn_kernel<<<dim3(8, 8, 16), dim3(512), 0, stream>>>(Qb, Kg2, Vt2, fw, fused);
    gemm_bt<1, 1><<<dim3(2560), dim3(256), 0, stream>>>(fused, wout_bt, (void*)out, 640, 640, 0L, 0L, 0L);
}